// Round 4
// baseline (983.401 us; speedup 1.0000x reference)
//
#include <hip/hip_runtime.h>
#include <math.h>

#define B_  64
#define S_  128
#define LW_ 20
#define CHAR_E_ 30
#define CHAR_C_ 30
#define WORD_E_ 300
#define H_  256
#define NC_ 25
#define F_  330
#define KP_ 352       // K padded to multiple of 32
#define G4_ 1024      // 4*H
#define NG_ 2048      // both directions' gates

typedef __attribute__((ext_vector_type(8))) short short8;
typedef __attribute__((ext_vector_type(4))) float floatx4;

__device__ __forceinline__ float sigmoidf_(float x){ return 1.0f/(1.0f+__expf(-x)); }
__device__ __forceinline__ float tanh_(float x){ return 1.0f - 2.0f/(1.0f+__expf(2.0f*x)); }

__device__ __forceinline__ unsigned int f2bf(float f){
    unsigned int u = __float_as_uint(f);
    u += 0x7FFFu + ((u>>16)&1u);
    return (u>>16) & 0xFFFFu;
}

// ---------------- init: zero output scalar ----------------
__global__ void k_init(float* out){
    if(blockIdx.x==0 && threadIdx.x==0) *out = 0.f;
}

// ---------------- pack w_ih (f then r) into bf16 (2048 x 352), zero-padded ----------------
__global__ void k_pack(const float* wf, const float* wr, unsigned short* wp){
    int i = blockIdx.x*256 + threadIdx.x;
    if(i >= NG_*KP_) return;
    int r = i / KP_, k = i % KP_;
    const float* src = (r < G4_) ? wf : wr;
    int rr = r & (G4_-1);
    wp[i] = (k < F_) ? (unsigned short)f2bf(src[(size_t)rr*F_ + k]) : 0;
}

// ---------------- word embedding gather into feat cols [0,300) bf16, zeros [330,352) ----------------
__global__ void k_wemb(const float* wt, const int* sent, unsigned short* feat){
    int idx = blockIdx.x*256 + threadIdx.x;
    if(idx >= B_*S_*76) return;
    int n = idx / 76, e4 = idx % 76;
    if(e4 < 75){
        float4 v = ((const float4*)(wt + (size_t)sent[n]*WORD_E_))[e4];
        unsigned int lo = f2bf(v.x) | (f2bf(v.y)<<16);
        unsigned int hi = f2bf(v.z) | (f2bf(v.w)<<16);
        uint2 pr; pr.x = lo; pr.y = hi;
        *(uint2*)(feat + (size_t)n*KP_ + e4*4) = pr;
    } else {
        unsigned int* z = (unsigned int*)(feat + (size_t)n*KP_ + 330);
        #pragma unroll
        for(int q=0;q<11;q++) z[q] = 0;
    }
}

// ---------------- char conv + maxpool into feat cols [300,330) bf16 ----------------
__global__ void k_charconv(const float* ct, const int* word, const float* cw,
                           const float* cb, unsigned short* feat){
    __shared__ __align__(16) float x[8][32][20];   // [tok][ic][t]
    int tok0 = blockIdx.x*8;
    for(int e = threadIdx.x; e < 8*32*20; e += 256){
        int t  = e % 20;
        int ic = (e/20) & 31;
        int tl = e / 640;
        int id = word[(size_t)(tok0+tl)*LW_ + t];
        float v = 0.f;
        if(ic < CHAR_E_ && id != 0) v = ct[(size_t)id*CHAR_E_ + ic];
        x[tl][ic][t] = v;
    }
    __syncthreads();
    int tid = threadIdx.x;
    if(tid < 240){
        int tl = tid/30, oc = tid%30;
        float acc[22];
        #pragma unroll
        for(int q=0;q<22;q++) acc[q] = 0.f;
        for(int ic=0; ic<CHAR_E_; ic++){
            float w0 = cw[(oc*CHAR_E_+ic)*3+0];
            float w1 = cw[(oc*CHAR_E_+ic)*3+1];
            float w2 = cw[(oc*CHAR_E_+ic)*3+2];
            const float* xr = &x[tl][ic][0];
            #pragma unroll
            for(int t4=0;t4<5;t4++){
                float4 v = ((const float4*)xr)[t4];
                int t0 = t4*4;
                acc[t0+2] += v.x*w0; acc[t0+1] += v.x*w1; acc[t0+0] += v.x*w2;
                acc[t0+3] += v.y*w0; acc[t0+2] += v.y*w1; acc[t0+1] += v.y*w2;
                acc[t0+4] += v.z*w0; acc[t0+3] += v.z*w1; acc[t0+2] += v.z*w2;
                acc[t0+5] += v.w*w0; acc[t0+4] += v.w*w1; acc[t0+3] += v.w*w2;
            }
        }
        float m = -1e30f;
        #pragma unroll
        for(int t=0;t<20;t++){ float v = acc[t+1]; m = fmaxf(m, v); }
        m += cb[oc];
        feat[(size_t)(tok0+tl)*KP_ + WORD_E_ + oc] = (unsigned short)f2bf(m);
    }
}

// ---------------- bf16 MFMA GEMM: gx = feat(8192x352) . wpack(2048x352)^T + bias ----------------
// 64x64 tile, 256 threads = 4 waves; wave w owns M-rows w*16..w*16+15, all 64 N.
__global__ __launch_bounds__(256) void k_gemm(const unsigned short* A, const unsigned short* Bw,
                                              const float* bf, const float* br, float* gx){
    __shared__ __align__(16) unsigned short As[64][40];
    __shared__ __align__(16) unsigned short Bs[64][40];
    int m0 = blockIdx.x*64, n0 = blockIdx.y*64;
    int tid = threadIdx.x;
    int w = tid>>6, lane = tid&63, q = lane>>4, l16 = lane&15;
    int srow = tid>>2, koff = (tid&3)*8;
    floatx4 acc0={0.f,0.f,0.f,0.f}, acc1=acc0, acc2=acc0, acc3=acc0;
    for(int k0=0; k0<KP_; k0+=32){
        uint4 av = *(const uint4*)(A  + (size_t)(m0+srow)*KP_ + k0 + koff);
        uint4 bv = *(const uint4*)(Bw + (size_t)(n0+srow)*KP_ + k0 + koff);
        __syncthreads();
        *(uint4*)&As[srow][koff] = av;
        *(uint4*)&Bs[srow][koff] = bv;
        __syncthreads();
        short8 af = *(const short8*)&As[w*16+l16][q*8];
        short8 b0 = *(const short8*)&Bs[l16][q*8];
        short8 b1 = *(const short8*)&Bs[16+l16][q*8];
        short8 b2 = *(const short8*)&Bs[32+l16][q*8];
        short8 b3 = *(const short8*)&Bs[48+l16][q*8];
        acc0 = __builtin_amdgcn_mfma_f32_16x16x32_bf16(af, b0, acc0, 0,0,0);
        acc1 = __builtin_amdgcn_mfma_f32_16x16x32_bf16(af, b1, acc1, 0,0,0);
        acc2 = __builtin_amdgcn_mfma_f32_16x16x32_bf16(af, b2, acc2, 0,0,0);
        acc3 = __builtin_amdgcn_mfma_f32_16x16x32_bf16(af, b3, acc3, 0,0,0);
    }
    // D layout: col = l16 -> n, row = q*4+r -> m
    #pragma unroll
    for(int nt=0; nt<4; nt++){
        floatx4 a = (nt==0)?acc0:(nt==1)?acc1:(nt==2)?acc2:acc3;
        int n = n0 + nt*16 + l16;
        int dirr = n >> 10, grow = n & 1023;
        float bias = dirr ? br[grow] : bf[grow];
        #pragma unroll
        for(int r=0; r<4; r++){
            int m = m0 + w*16 + q*4 + r;
            int b = m >> 7, s = m & 127;
            gx[(((size_t)dirr*S_ + s)*B_ + b)*G4_ + grow] = a[r] + bias;
        }
    }
}

// ---------------- persistent biLSTM: one block per (dir, 16-batch group) ----------------
// 8 blocks x 1024 threads (16 waves). Whole-direction w_hh (1024x256) as fp8 e4m3
// (scaled x64) in 64 VGPRs/lane. h (scaled x16, fp8) in 4KB LDS. No cross-block sync.
__global__ __launch_bounds__(1024,4) void k_lstm_all(const float* whhf, const float* whhr,
        const float* gx, float* hseq)
{
    int bid = blockIdx.x;        // 0..7
    int dir = bid >> 2;
    int bg  = bid & 3;
    int tid = threadIdx.x;
    int w    = tid >> 6;         // wave 0..15: units w*16..w*16+15
    int lane = tid & 63;
    int q    = lane >> 4;
    int l16  = lane & 15;

    __shared__ __align__(16) unsigned char hlds[16*264];   // [batch][unit] fp8, +8B row pad

    const float* whh = dir ? whhr : whhf;

    // one-time: convert my weight slice to fp8 A-fragments (rows g*256+w*16+l16, k=kt*32+q*8+j)
    long wreg[4][8];
    #pragma unroll
    for(int g=0; g<4; g++){
        const float* rp = whh + (size_t)(g*H_ + w*16 + l16)*H_;
        #pragma unroll
        for(int kt=0; kt<8; kt++){
            const float* p = rp + kt*32 + q*8;
            unsigned int d0 = 0, d1 = 0;
            d0 = __builtin_amdgcn_cvt_pk_fp8_f32(p[0]*64.f, p[1]*64.f, d0, false);
            d0 = __builtin_amdgcn_cvt_pk_fp8_f32(p[2]*64.f, p[3]*64.f, d0, true);
            d1 = __builtin_amdgcn_cvt_pk_fp8_f32(p[4]*64.f, p[5]*64.f, d1, false);
            d1 = __builtin_amdgcn_cvt_pk_fp8_f32(p[6]*64.f, p[7]*64.f, d1, true);
            wreg[g][kt] = (long)(((unsigned long long)d1 << 32) | d0);
        }
    }

    // zero h(t=-1)
    for(int i = tid; i < 16*264/4; i += 1024) ((unsigned int*)hlds)[i] = 0;
    __syncthreads();

    int b_glob = bg*16 + l16;
    int u0     = w*16 + q*4;
    const float inv_sc = 1.0f/1024.f;    // w x64, h x16

    float cc0=0.f, cc1=0.f, cc2=0.f, cc3=0.f;

    for(int t=0; t<S_; t++){
        int s = dir ? (S_-1-t) : t;

        floatx4 g0, g1, g2, g3;
        {
            const float* gp = gx + (((size_t)dir*S_ + s)*B_ + b_glob)*G4_ + u0;
            g0 = *(const floatx4*)(gp);
            g1 = *(const floatx4*)(gp + H_);
            g2 = *(const floatx4*)(gp + 2*H_);
            g3 = *(const floatx4*)(gp + 3*H_);
        }

        floatx4 a0={0.f,0.f,0.f,0.f}, a1=a0, a2=a0, a3=a0;
        #pragma unroll
        for(int kt=0; kt<8; kt++){
            long hb = *(const long*)&hlds[l16*264 + kt*32 + q*8];
            a0 = __builtin_amdgcn_mfma_f32_16x16x32_fp8_fp8(wreg[0][kt], hb, a0, 0,0,0);
            a1 = __builtin_amdgcn_mfma_f32_16x16x32_fp8_fp8(wreg[1][kt], hb, a1, 0,0,0);
            a2 = __builtin_amdgcn_mfma_f32_16x16x32_fp8_fp8(wreg[2][kt], hb, a2, 0,0,0);
            a3 = __builtin_amdgcn_mfma_f32_16x16x32_fp8_fp8(wreg[3][kt], hb, a3, 0,0,0);
        }

        float hv0, hv1, hv2, hv3;
        {
            float iv, fv, gv, ov, cn;
            iv=a0[0]*inv_sc+g0[0]; fv=a1[0]*inv_sc+g1[0]; gv=a2[0]*inv_sc+g2[0]; ov=a3[0]*inv_sc+g3[0];
            cn = sigmoidf_(fv)*cc0 + sigmoidf_(iv)*tanh_(gv); cc0=cn; hv0 = sigmoidf_(ov)*tanh_(cn);
            iv=a0[1]*inv_sc+g0[1]; fv=a1[1]*inv_sc+g1[1]; gv=a2[1]*inv_sc+g2[1]; ov=a3[1]*inv_sc+g3[1];
            cn = sigmoidf_(fv)*cc1 + sigmoidf_(iv)*tanh_(gv); cc1=cn; hv1 = sigmoidf_(ov)*tanh_(cn);
            iv=a0[2]*inv_sc+g0[2]; fv=a1[2]*inv_sc+g1[2]; gv=a2[2]*inv_sc+g2[2]; ov=a3[2]*inv_sc+g3[2];
            cn = sigmoidf_(fv)*cc2 + sigmoidf_(iv)*tanh_(gv); cc2=cn; hv2 = sigmoidf_(ov)*tanh_(cn);
            iv=a0[3]*inv_sc+g0[3]; fv=a1[3]*inv_sc+g1[3]; gv=a2[3]*inv_sc+g2[3]; ov=a3[3]*inv_sc+g3[3];
            cn = sigmoidf_(fv)*cc3 + sigmoidf_(iv)*tanh_(gv); cc3=cn; hv3 = sigmoidf_(ov)*tanh_(cn);
        }

        *(float4*)(hseq + (((size_t)dir*S_ + s)*B_ + b_glob)*H_ + u0) = make_float4(hv0,hv1,hv2,hv3);

        __syncthreads();   // everyone done reading h(t-1)
        unsigned int hd = 0;
        hd = __builtin_amdgcn_cvt_pk_fp8_f32(hv0*16.f, hv1*16.f, hd, false);
        hd = __builtin_amdgcn_cvt_pk_fp8_f32(hv2*16.f, hv3*16.f, hd, true);
        *(unsigned int*)&hlds[l16*264 + u0] = hd;
        __syncthreads();   // h(t) fully published
    }
}

// ---------------- emissions: block = 8 (s,b) pairs, h staged in LDS ----------------
__global__ __launch_bounds__(256) void k_em(const float* hseq, const float* lw, const float* lb, float* em){
    __shared__ __align__(16) float hb[8][516];   // +4 pad: conflict-free p-groups
    int sb0 = blockIdx.x*8;
    int tid = threadIdx.x;
    for(int i = tid; i < 1024; i += 256){
        int p = i >> 7, r = i & 127;
        int sb = sb0 + p, s = sb >> 6, b = sb & 63;
        const float* src = (r < 64) ? (hseq + (((size_t)0*S_+s)*B_+b)*H_ + r*4)
                                    : (hseq + (((size_t)1*S_+s)*B_+b)*H_ + (r-64)*4);
        *(float4*)&hb[p][r*4] = *(const float4*)src;
    }
    __syncthreads();
    if(tid < 200){
        int p = tid / 25, nc = tid % 25;
        const float4* wv = (const float4*)(lw + (size_t)nc*2*H_);
        const float4* hv = (const float4*)&hb[p][0];
        float acc = lb[nc];
        #pragma unroll 16
        for(int k=0;k<128;k++){ float4 a=hv[k], ww=wv[k]; acc += a.x*ww.x + a.y*ww.y + a.z*ww.z + a.w*ww.w; }
        em[(size_t)(sb0+p)*NC_ + nc] = acc;
    }
}

// ---------------- CRF NLL: one block (64 threads) per batch; out += logZ - score ----------------
__global__ void k_crf(const float* em, const int* tag, const void* mask,
                      const float* st, const float* et, const float* tr, float* out){
    __shared__ float trs[NC_*NC_];
    __shared__ float alpha[2][NC_];
    __shared__ float score_sh;
    __shared__ int   len_sh;
    int b = blockIdx.x, tid = threadIdx.x;
    for(int i=tid;i<NC_*NC_;i+=64) trs[i]=tr[i];
    unsigned int first = *(const unsigned int*)mask;
    int ml;  // 0=int32, 1=uint8, 2=float32
    if(first == 1u) ml = 0;
    else if(first == 0x3F800000u) ml = 2;
    else ml = 1;
    __syncthreads();

    float part = 0.f; int cnt = 0;
    for(int s = tid; s < S_; s += 64){
        float mkv;
        {
            int off = b*S_ + s;
            if(ml==0)      mkv = ((const int*)mask)[off] ? 1.f : 0.f;
            else if(ml==1) mkv = ((const unsigned char*)mask)[off] ? 1.f : 0.f;
            else           mkv = ((const float*)mask)[off];
        }
        cnt += (mkv != 0.f) ? 1 : 0;
        if(s == 0){
            int t0 = tag[b*S_];
            part += st[t0] + em[((size_t)0*B_ + b)*NC_ + t0];
        } else {
            int tp = tag[b*S_ + s-1], tc = tag[b*S_ + s];
            part += mkv * (trs[tp*NC_ + tc] + em[((size_t)s*B_ + b)*NC_ + tc]);
        }
    }
    for(int o=32;o>0;o>>=1){ part += __shfl_down(part, o); cnt += __shfl_down(cnt, o); }
    if(tid==0){ len_sh = cnt; score_sh = part; }
    __syncthreads();
    float score = 0.f;
    if(tid == 0){
        int last = len_sh - 1;
        score = score_sh + et[ tag[b*S_ + last] ];
    }

    if(tid < NC_) alpha[0][tid] = st[tid] + em[((size_t)0*B_ + b)*NC_ + tid];
    __syncthreads();
    int cur = 0;
    for(int s=1;s<S_;s++){
        float nv = 0.f;
        if(tid < NC_){
            int j = tid;
            float m = -1e30f;
            #pragma unroll
            for(int i=0;i<NC_;i++){ float v = alpha[cur][i] + trs[i*NC_+j]; m = fmaxf(m, v); }
            float sum = 0.f;
            #pragma unroll
            for(int i=0;i<NC_;i++){ sum += __expf(alpha[cur][i] + trs[i*NC_+j] - m); }
            float nxt = m + __logf(sum) + em[((size_t)s*B_ + b)*NC_ + j];
            float mkv;
            {
                int off = b*S_ + s;
                if(ml==0)      mkv = ((const int*)mask)[off] ? 1.f : 0.f;
                else if(ml==1) mkv = ((const unsigned char*)mask)[off] ? 1.f : 0.f;
                else           mkv = ((const float*)mask)[off];
            }
            nv = (mkv != 0.f) ? nxt : alpha[cur][j];
        }
        __syncthreads();
        if(tid < NC_) alpha[cur^1][tid] = nv;
        __syncthreads();
        cur ^= 1;
    }
    float v = (tid < NC_) ? (alpha[cur][tid] + et[tid]) : -1e30f;
    float m = v;
    for(int o=32;o>0;o>>=1) m = fmaxf(m, __shfl_down(m, o));
    m = __shfl(m, 0);
    float e = (tid < NC_) ? __expf(v - m) : 0.f;
    for(int o=32;o>0;o>>=1) e += __shfl_down(e, o);
    if(tid == 0){
        float logZ = m + __logf(e);
        atomicAdd(out, logZ - score);
    }
}

extern "C" void kernel_launch(void* const* d_in, const int* in_sizes, int n_in,
                              void* d_out, int out_size, void* d_ws, size_t ws_size,
                              hipStream_t stream) {
    const float* word_table = (const float*)d_in[0];
    const float* char_table = (const float*)d_in[1];
    const float* conv_w     = (const float*)d_in[2];
    const float* conv_b     = (const float*)d_in[3];
    const float* w_ih_f     = (const float*)d_in[4];
    const float* w_hh_f     = (const float*)d_in[5];
    const float* b_f        = (const float*)d_in[6];
    const float* w_ih_r     = (const float*)d_in[7];
    const float* w_hh_r     = (const float*)d_in[8];
    const float* b_r        = (const float*)d_in[9];
    const float* lin_w      = (const float*)d_in[10];
    const float* lin_b      = (const float*)d_in[11];
    const float* start_t    = (const float*)d_in[12];
    const float* end_t      = (const float*)d_in[13];
    const float* trans      = (const float*)d_in[14];
    const int*   sent       = (const int*)d_in[15];
    const int*   word       = (const int*)d_in[16];
    const int*   tag        = (const int*)d_in[17];
    const void*  mask       = d_in[18];
    float* out = (float*)d_out;

    char* ws = (char*)d_ws;
    unsigned short* feat  = (unsigned short*)ws;                 // 8192*352*2  = 5,767,168 B
    unsigned short* wpack = (unsigned short*)(ws + 5767168);     // 2048*352*2  = 1,441,792 B
    float* gx   = (float*)(ws + 5767168 + 1441792);              // 16,777,216 f = 67,108,864 B
    float* hseq = (float*)(ws + 5767168 + 1441792 + 67108864);   // 4,194,304 f = 16,777,216 B
    float* em   = (float*)(ws + 5767168 + 1441792 + 67108864 + 16777216);  // 204,800 f

    k_init<<<dim3(1), 64, 0, stream>>>(out);
    k_pack<<<dim3((NG_*KP_+255)/256), 256, 0, stream>>>(w_ih_f, w_ih_r, wpack);
    k_wemb<<<dim3((B_*S_*76+255)/256), 256, 0, stream>>>(word_table, sent, feat);
    k_charconv<<<dim3(B_*S_/8), 256, 0, stream>>>(char_table, word, conv_w, conv_b, feat);
    k_gemm<<<dim3(B_*S_/64, NG_/64), 256, 0, stream>>>(feat, wpack, b_f, b_r, gx);
    k_lstm_all<<<dim3(8), 1024, 0, stream>>>(w_hh_f, w_hh_r, gx, hseq);
    k_em<<<dim3(S_*B_/8), 256, 0, stream>>>(hseq, lin_w, lin_b, em);
    k_crf<<<dim3(B_), 64, 0, stream>>>(em, tag, mask, start_t, end_t, trans, out);
}